// Round 5
// baseline (235.620 us; speedup 1.0000x reference)
//
#include <hip/hip_runtime.h>
#include <hip/hip_bf16.h>

// out[b,o,hw] = sum_c W[o,c] * relu(x[b,c,hw]*scale[c] + shift[c])
// B=256, Cin=2112, Cout=192, HW=49, all fp32 in HBM. bf16 MFMA internally.
//
// R5: R4's barrier-free register-gather structure + K-SPLIT x3.
// 66 K-steps = 3 chunks x 22 (uniform trip -> fully static unroll).
// Grid 1536 = 256 batch x 2 Cout-half x 3 K-chunk = exactly 6 blocks/CU
// co-resident: 3x shorter serial latency chain per block, 3x more
// independent chains per CU. Partials merged with fp32 atomicAdd into
// d_out (zeroed by hipMemsetAsync on-stream). Overlapping hw-windows are
// masked in the epilogue so each column is added exactly once per block.

#define CIN    2112
#define COUT   192
#define HWS    49
#define BK     32
#define NSTEP  (CIN / BK)     // 66
#define KSPLIT 3
#define LSTEP  (NSTEP / KSPLIT)  // 22
#define CSLICE (LSTEP * BK)      // 704 channels per K-chunk
#define EPSV   1e-5f

typedef __bf16 bf16;
typedef __attribute__((ext_vector_type(8))) __bf16 bf16x8;
typedef __attribute__((ext_vector_type(4))) float  f32x4;

// ---------- kernel 1: W fp32 -> bf16 in A-fragment order ----------
// Wb[((ks*12 + gmt)*64 + lane)*8 + j] = W[(gmt*16+(lane&15))*CIN + ks*32+(lane>>4)*8+j]
__global__ __launch_bounds__(256)
void w_repack_kernel(const float* __restrict__ W, bf16* __restrict__ Wb) {
    const int t = blockIdx.x * 256 + threadIdx.x;       // 66*12*64 = 50688
    if (t >= NSTEP * 12 * 64) return;
    const int lane = t & 63;
    const int gmt  = (t >> 6) % 12;
    const int ks   = t / (12 * 64);
    const int row  = gmt * 16 + (lane & 15);
    const int k    = ks * BK + (lane >> 4) * 8;
    const float* src = W + (size_t)row * CIN + k;
    f32x4 a = *(const f32x4*)src;
    f32x4 b = *(const f32x4*)(src + 4);
    bf16x8 o;
    #pragma unroll
    for (int j = 0; j < 4; j++) { o[j] = (bf16)a[j]; o[j + 4] = (bf16)b[j]; }
    *(bf16x8*)(Wb + (size_t)t * 8) = o;
}

// ---------- kernel 2: main GEMM (K-chunk partial, atomic accumulate) ----------
__global__ __launch_bounds__(256, 4)
void bnrelu_conv1x1_kernel(const float* __restrict__ x,
                           const float* __restrict__ gamma,
                           const float* __restrict__ beta,
                           const float* __restrict__ rmean,
                           const float* __restrict__ rvar,
                           const bf16*  __restrict__ Wb,
                           float* __restrict__ out)
{
    __shared__ __align__(16) float ssf[2 * CSLICE];  // [2i]=scale, [2i+1]=shift

    const int tid  = threadIdx.x;
    const int bid  = blockIdx.x;          // 256*6
    const int b    = bid / 6;
    const int sub  = bid % 6;
    const int half = sub & 1;             // Cout split: rows half*96..
    const int kq   = sub >> 1;            // K chunk 0..2
    const int gmt0 = half * 6;
    const int ks0  = kq * LSTEP;          // global first k-step
    const int c0   = ks0 * BK;            // first channel of this chunk

    const int lane = tid & 63;
    const int wv   = tid >> 6;
    const int l15  = lane & 15;
    const int q    = lane >> 4;
    const int hw0  = wv * 11;             // windows 0..15,11..26,22..37,33..48

    // per-lane bases
    const float* xL  = x + (size_t)b * (CIN * HWS) + (size_t)(c0 + q * 8) * HWS + hw0 + l15;
    const bf16*  wbL = Wb + (((size_t)ks0 * 12 + gmt0) * 64 + lane) * 8;
    const float* ssq = ssf + q * 16;

    // ---- prime prefetch rings: x depth 3, Wb depth 2 (issue ASAP) ----
    float  xr[3][8];
    bf16x8 wr[2][6];
    #pragma unroll
    for (int d = 0; d < 3; d++) {
        const float* p = xL + d * (BK * HWS);
        #pragma unroll
        for (int j = 0; j < 8; j++) xr[d][j] = p[j * HWS];
    }
    #pragma unroll
    for (int d = 0; d < 2; d++) {
        const bf16* p = wbL + (size_t)d * (12 * 64 * 8);
        #pragma unroll
        for (int mt = 0; mt < 6; mt++) wr[d][mt] = *(const bf16x8*)(p + mt * (64 * 8));
    }

    // ---- BN table for this chunk's 704 channels ----
    for (int i = tid; i < CSLICE; i += 256) {
        const int c = c0 + i;
        float inv = rsqrtf(rvar[c] + EPSV);
        float s   = gamma[c] * inv;
        ssf[2 * i]     = s;
        ssf[2 * i + 1] = beta[c] - rmean[c] * s;
    }

    f32x4 acc[6];
    #pragma unroll
    for (int i = 0; i < 6; i++) acc[i] = (f32x4)(0.f);

    __syncthreads();   // ssf ready (only barrier in the kernel)

    #pragma unroll
    for (int j = 0; j < LSTEP; j++) {
        const int s3 = j % 3;
        const int s2 = j & 1;

        // BN params for this step's 8 channels (broadcast LDS reads)
        const float* sb = ssq + j * 64;
        f32x4 p0 = *(const f32x4*)(sb);
        f32x4 p1 = *(const f32x4*)(sb + 4);
        f32x4 p2 = *(const f32x4*)(sb + 8);
        f32x4 p3 = *(const f32x4*)(sb + 12);
        float sc[8], sh[8];
        sc[0]=p0[0]; sh[0]=p0[1]; sc[1]=p0[2]; sh[1]=p0[3];
        sc[2]=p1[0]; sh[2]=p1[1]; sc[3]=p1[2]; sh[3]=p1[3];
        sc[4]=p2[0]; sh[4]=p2[1]; sc[5]=p2[2]; sh[5]=p2[3];
        sc[6]=p3[0]; sh[6]=p3[1]; sc[7]=p3[2]; sh[7]=p3[3];

        // consume x ring -> B-fragment (BN + ReLU + cvt)
        bf16x8 bfrag;
        #pragma unroll
        for (int j2 = 0; j2 < 8; j2++)
            bfrag[j2] = (bf16)fmaxf(fmaf(xr[s3][j2], sc[j2], sh[j2]), 0.f);

        // refill x ring with step j+3 (clamped; duplicate tail loads unused)
        {
            int kf = j + 3; if (kf > LSTEP - 1) kf = LSTEP - 1;
            const float* p = xL + kf * (BK * HWS);
            #pragma unroll
            for (int j2 = 0; j2 < 8; j2++) xr[s3][j2] = p[j2 * HWS];
        }

        // MFMA: 6 m-tiles
        #pragma unroll
        for (int mt = 0; mt < 6; mt++)
            acc[mt] = __builtin_amdgcn_mfma_f32_16x16x32_bf16(wr[s2][mt], bfrag, acc[mt], 0, 0, 0);

        // refill Wb ring with step j+2 (clamped)
        {
            int kf = j + 2; if (kf > LSTEP - 1) kf = LSTEP - 1;
            const bf16* p = wbL + (size_t)kf * (12 * 64 * 8);
            #pragma unroll
            for (int mt = 0; mt < 6; mt++) wr[s2][mt] = *(const bf16x8*)(p + mt * (64 * 8));
        }
    }

    // ---- epilogue: C/D layout col=lane&15 -> hw, row=q*4+r -> m ----
    // Mask overlap between hw-windows: wave wv owns cols [11*wv, 11*wv+11)
    // (wave 3 owns [33,49)) so each element is atomically added exactly once.
    const int hw = hw0 + l15;
    const int mbase = half * 96;
    const bool writer = (wv == 3) || (l15 < 11);
    if (writer) {
        #pragma unroll
        for (int mt = 0; mt < 6; mt++) {
            #pragma unroll
            for (int r = 0; r < 4; r++) {
                const int row = mbase + mt * 16 + q * 4 + r;
                atomicAdd(&out[((size_t)b * COUT + row) * HWS + hw], acc[mt][r]);
            }
        }
    }
}

extern "C" void kernel_launch(void* const* d_in, const int* in_sizes, int n_in,
                              void* d_out, int out_size, void* d_ws, size_t ws_size,
                              hipStream_t stream) {
    const float* x     = (const float*)d_in[0];
    const float* gamma = (const float*)d_in[1];
    const float* beta  = (const float*)d_in[2];
    const float* rmean = (const float*)d_in[3];
    const float* rvar  = (const float*)d_in[4];
    const float* W     = (const float*)d_in[5];
    float* out = (float*)d_out;

    bf16* Wb = (bf16*)d_ws;   // 66*12*64*8 bf16 = 811008 B of scratch

    hipMemsetAsync(out, 0, (size_t)out_size * sizeof(float), stream);
    w_repack_kernel<<<dim3(198), dim3(256), 0, stream>>>(W, Wb);
    bnrelu_conv1x1_kernel<<<dim3(256 * 6), dim3(256), 0, stream>>>(
        x, gamma, beta, rmean, rvar, Wb, out);
}